// Round 17
// baseline (507.282 us; speedup 1.0000x reference)
//
#include <hip/hip_runtime.h>
#include <hip/hip_cooperative_groups.h>
#include <math.h>

namespace cg = cooperative_groups;

#define NN   8
#define INCH 32
#define INN  50000
#define OUTC 64
#define OUTN 8192
#define DD   32
#define CC   256            // NN*INCH
#define NPL  8              // c-planes (== #XCDs)
#define PLDW ((size_t)INN * 16)   // dwords per plane: 50000 rows x 16 dwords(64B) = 3.2 MB
#define JWF  196            // fused prep j-window: 256 chunks x 196 >= 50000
#define JW   512            // fallback prep j-window

typedef unsigned short ushortT;

__device__ __forceinline__ unsigned f2bf_u(float f) {
  unsigned u = __float_as_uint(f);
  return (u + 0x7FFFu + ((u >> 16) & 1u)) >> 16;   // round-nearest-even
}

// dword convention: yTc plane p, row j, pos q (0..15) holds bf16 pair (c_lo, c_lo+128),
// c_lo = p*16 + q.

// ============ FUSED cooperative kernel: prep -> gather -> out ============
// 2048 blocks x 256 thr = 8 blocks/CU (LDS 13.4KB, VGPR<=64 via launch_bounds).
// Block b pins to XCD b%8 (round-robin dispatch): prep writes plane b&7 into its
// own XCD L2; gather (same b&7) reads it back -> yTc never round-trips HBM.
__global__ __launch_bounds__(256, 8) void fused_kernel(
    const float* __restrict__ x, const float* __restrict__ nf,
    const int* __restrict__ A, const float* __restrict__ ft,
    const float* __restrict__ bias, unsigned* __restrict__ yTc,
    unsigned* __restrict__ red32, float* __restrict__ out) {
  __shared__ __align__(16) char smem[13344];   // union: prep 13.3K | gather 4.3K | out 12.4K
  const int t = threadIdx.x;
  const int b = blockIdx.x;
  const int p  = b & 7;            // plane == XCD
  const int b2 = b >> 3;           // 0..255
  cg::grid_group grid = cg::this_grid();

  // ---------------- phase A: prep (slab, JWF=196) ----------------
  {
    ushortT (*tile)[34] = (ushortT(*)[34])smem;   // [JWF][34]
    const int j0 = b2 * JWF;
    const int jmax = min(JWF, INN - j0);          // >0 for all b2 (255*196=49980)

    const int rl = t >> 3;                        // row_local 0..31
    const int m  = t & 7;
    const int cg_row = p * 16 + (rl & 15) + ((rl >> 4) << 7);
    const int slot = ((rl & 15) << 1) | (rl >> 4);
    const float* xr = x + (size_t)cg_row * INN + j0;
    const float* nr = nf + (size_t)(((p & 1) << 4) + (rl & 15)) * INN + j0;

    #pragma unroll
    for (int i = 0; i < 7; ++i) {                 // covers j 0..223 >= 196
      const int jj = i * 32 + m * 4;
      if (jj < jmax) {
        const float4 xv = *(const float4*)(xr + jj);
        const float4 nv = *(const float4*)(nr + jj);
        tile[jj + 0][slot] = (ushortT)f2bf_u(xv.x * nv.x);
        tile[jj + 1][slot] = (ushortT)f2bf_u(xv.y * nv.y);
        tile[jj + 2][slot] = (ushortT)f2bf_u(xv.z * nv.z);
        tile[jj + 3][slot] = (ushortT)f2bf_u(xv.w * nv.w);
      }
    }
    __syncthreads();

    unsigned* dst = yTc + (size_t)p * PLDW + (size_t)j0 * 16;
    const int ndw = jmax * 16;
    for (int dw = t; dw < ndw; dw += 256)
      dst[dw] = *(const unsigned*)&tile[dw >> 4][2 * (dw & 15)];
    __syncthreads();
  }

  grid.sync();   // prep complete, device-visible

  // ---------------- phase B: gather (R11 structure) ----------------
  {
    int* Al = (int*)smem;                         // [32*33]
    const int o0 = b2 * 32;
    #pragma unroll
    for (int k = 0; k < 4; ++k) {
      const int f = k * 256 + t;
      Al[(f >> 5) * 33 + (f & 31)] = A[(size_t)o0 * DD + f];
    }
    __syncthreads();

    const unsigned* plane = yTc + (size_t)p * PLDW;
    const int osub = t >> 3;
    const int cq   = (t >> 1) & 3;
    const int dh   = t & 1;

    float l0 = -INFINITY, l1 = -INFINITY, l2 = -INFINITY, l3 = -INFINITY;
    float h0 = -INFINITY, h1 = -INFINITY, h2 = -INFINITY, h3 = -INFINITY;

    #pragma unroll 8
    for (int k = 0; k < 16; ++k) {
      const int d = 2 * k + dh;
      const int idx = Al[osub * 33 + d];          // conflict-free broadcast
      const uint4 v = *(const uint4*)(plane + (size_t)idx * 16 + cq * 4);   // L2-hot
      l0 = fmaxf(l0, __uint_as_float(v.x << 16));  h0 = fmaxf(h0, __uint_as_float(v.x & 0xffff0000u));
      l1 = fmaxf(l1, __uint_as_float(v.y << 16));  h1 = fmaxf(h1, __uint_as_float(v.y & 0xffff0000u));
      l2 = fmaxf(l2, __uint_as_float(v.z << 16));  h2 = fmaxf(h2, __uint_as_float(v.z & 0xffff0000u));
      l3 = fmaxf(l3, __uint_as_float(v.w << 16));  h3 = fmaxf(h3, __uint_as_float(v.w & 0xffff0000u));
    }
    l0 = fmaxf(l0, __shfl_xor(l0, 1));  h0 = fmaxf(h0, __shfl_xor(h0, 1));
    l1 = fmaxf(l1, __shfl_xor(l1, 1));  h1 = fmaxf(h1, __shfl_xor(h1, 1));
    l2 = fmaxf(l2, __shfl_xor(l2, 1));  h2 = fmaxf(h2, __shfl_xor(h2, 1));
    l3 = fmaxf(l3, __shfl_xor(l3, 1));  h3 = fmaxf(h3, __shfl_xor(h3, 1));

    uint2 pk;
    if (dh == 0) {
      pk.x = (__float_as_uint(l0) >> 16) | (__float_as_uint(h0) & 0xffff0000u);
      pk.y = (__float_as_uint(l1) >> 16) | (__float_as_uint(h1) & 0xffff0000u);
    } else {
      pk.x = (__float_as_uint(l2) >> 16) | (__float_as_uint(h2) & 0xffff0000u);
      pk.y = (__float_as_uint(l3) >> 16) | (__float_as_uint(h3) & 0xffff0000u);
    }
    *(uint2*)(red32 + (size_t)(o0 + osub) * 128 + p * 16 + cq * 4 + dh * 2) = pk;
  }

  grid.sync();   // red32 complete, device-visible

  // ---------------- phase C: out (quarter tiles: 16 o x c-half) ----------------
  {
    float* rtile = (float*)smem;                  // [16][65]
    float* ftl   = (float*)(smem + 16 * 65 * 4);  // [32][64]
    const int np = b >> 9;                        // 0..3
    const int o0 = (b & 511) * 16;
    const int hi = np >> 1;
    const int sb = (np & 1) * 64;

    #pragma unroll
    for (int q = 0; q < 8; ++q) {
      const int idx = q * 256 + t;
      ftl[idx] = ft[idx];
    }
    {
      const int r = t >> 4;                       // 0..15
      const int g = t & 15;
      const uint4 v = *(const uint4*)(red32 + (size_t)(o0 + r) * 128 + sb + g * 4);
      const unsigned w[4] = {v.x, v.y, v.z, v.w};
      float* dst = &rtile[r * 65 + g * 4];
      #pragma unroll
      for (int u = 0; u < 4; ++u)
        dst[u] = __uint_as_float(hi ? (w[u] & 0xffff0000u) : (w[u] << 16));
    }
    __syncthreads();

    const int w  = t >> 6;                        // wave 0..3
    const int lane = t & 63;
    const int o_l = lane & 15;
    const int kb  = lane >> 4;                    // 0..3
    const int n   = 2 * np + (w & 1);
    const int kh  = (w >> 1) * 32 + kb * 8;
    const int cb  = (w & 1) * 32;

    float acc[8];
    #pragma unroll
    for (int kk = 0; kk < 8; ++kk) acc[kk] = 0.f;
    #pragma unroll
    for (int i = 0; i < 32; ++i) {
      const float rv = rtile[o_l * 65 + cb + i];  // 16 addrs, 4-way broadcast
      #pragma unroll
      for (int kk = 0; kk < 8; ++kk)
        acc[kk] += rv * ftl[i * 64 + kh + kk];    // 4 addrs, broadcast
    }

    float* op = out + (size_t)n * OUTC * OUTN + o0 + o_l;
    const float* bp = bias + o0 + o_l;
    #pragma unroll
    for (int kk = 0; kk < 8; ++kk) {
      const int k = kh + kk;
      op[(size_t)k * OUTN] = acc[kk] + bp[(size_t)k * OUTN];   // 64B segments
    }
  }
}

// ============ Fallback path (proven R15/R11/R14 kernels) ============
__global__ __launch_bounds__(256) void prep_kernel(
    const float* __restrict__ x, const float* __restrict__ nf, unsigned* __restrict__ yTc) {
  __shared__ ushortT tile[JW][34];
  const int t = threadIdx.x;
  const int p  = blockIdx.x & 7;
  const int b2 = blockIdx.x >> 3;
  const int j0 = b2 * JW;
  const int jmax = min(JW, INN - j0);

  const int rl = t >> 3;
  const int m  = t & 7;
  const int cg_row = p * 16 + (rl & 15) + ((rl >> 4) << 7);
  const int slot = ((rl & 15) << 1) | (rl >> 4);
  const float* xr = x + (size_t)cg_row * INN + j0;
  const float* nr = nf + (size_t)(((p & 1) << 4) + (rl & 15)) * INN + j0;

  #pragma unroll 8
  for (int i = 0; i < 16; ++i) {
    const int jj = i * 32 + m * 4;
    if (jj < jmax) {
      const float4 xv = *(const float4*)(xr + jj);
      const float4 nv = *(const float4*)(nr + jj);
      tile[jj + 0][slot] = (ushortT)f2bf_u(xv.x * nv.x);
      tile[jj + 1][slot] = (ushortT)f2bf_u(xv.y * nv.y);
      tile[jj + 2][slot] = (ushortT)f2bf_u(xv.z * nv.z);
      tile[jj + 3][slot] = (ushortT)f2bf_u(xv.w * nv.w);
    }
  }
  __syncthreads();

  unsigned* dst = yTc + (size_t)p * PLDW + (size_t)j0 * 16;
  const int ndw = jmax * 16;
  for (int dw = t; dw < ndw; dw += 256)
    dst[dw] = *(const unsigned*)&tile[dw >> 4][2 * (dw & 15)];
}

__global__ __launch_bounds__(256, 8) void gather_kernel(
    const unsigned* __restrict__ yTc, const int* __restrict__ A, unsigned* __restrict__ red32) {
  __shared__ int Al[32 * 33];
  const int t = threadIdx.x;
  const int ck = blockIdx.x & 7;
  const int ob = blockIdx.x >> 3;
  const int o0 = ob * 32;

  #pragma unroll
  for (int k = 0; k < 4; ++k) {
    const int f = k * 256 + t;
    Al[(f >> 5) * 33 + (f & 31)] = A[(size_t)o0 * DD + f];
  }
  __syncthreads();

  const unsigned* plane = yTc + (size_t)ck * PLDW;
  const int osub = t >> 3;
  const int cq   = (t >> 1) & 3;
  const int dh   = t & 1;

  float l0 = -INFINITY, l1 = -INFINITY, l2 = -INFINITY, l3 = -INFINITY;
  float h0 = -INFINITY, h1 = -INFINITY, h2 = -INFINITY, h3 = -INFINITY;

  #pragma unroll 8
  for (int k = 0; k < 16; ++k) {
    const int d = 2 * k + dh;
    const int idx = Al[osub * 33 + d];
    const uint4 v = *(const uint4*)(plane + (size_t)idx * 16 + cq * 4);
    l0 = fmaxf(l0, __uint_as_float(v.x << 16));  h0 = fmaxf(h0, __uint_as_float(v.x & 0xffff0000u));
    l1 = fmaxf(l1, __uint_as_float(v.y << 16));  h1 = fmaxf(h1, __uint_as_float(v.y & 0xffff0000u));
    l2 = fmaxf(l2, __uint_as_float(v.z << 16));  h2 = fmaxf(h2, __uint_as_float(v.z & 0xffff0000u));
    l3 = fmaxf(l3, __uint_as_float(v.w << 16));  h3 = fmaxf(h3, __uint_as_float(v.w & 0xffff0000u));
  }
  l0 = fmaxf(l0, __shfl_xor(l0, 1));  h0 = fmaxf(h0, __shfl_xor(h0, 1));
  l1 = fmaxf(l1, __shfl_xor(l1, 1));  h1 = fmaxf(h1, __shfl_xor(h1, 1));
  l2 = fmaxf(l2, __shfl_xor(l2, 1));  h2 = fmaxf(h2, __shfl_xor(h2, 1));
  l3 = fmaxf(l3, __shfl_xor(l3, 1));  h3 = fmaxf(h3, __shfl_xor(h3, 1));

  uint2 pk;
  if (dh == 0) {
    pk.x = (__float_as_uint(l0) >> 16) | (__float_as_uint(h0) & 0xffff0000u);
    pk.y = (__float_as_uint(l1) >> 16) | (__float_as_uint(h1) & 0xffff0000u);
  } else {
    pk.x = (__float_as_uint(l2) >> 16) | (__float_as_uint(h2) & 0xffff0000u);
    pk.y = (__float_as_uint(l3) >> 16) | (__float_as_uint(h3) & 0xffff0000u);
  }
  *(uint2*)(red32 + (size_t)(o0 + osub) * 128 + ck * 16 + cq * 4 + dh * 2) = pk;
}

__global__ __launch_bounds__(256) void out_kernel(
    const unsigned* __restrict__ red32, const float* __restrict__ ft,
    const float* __restrict__ bias, float* __restrict__ out) {
  __shared__ float rtile[64][65];
  __shared__ float ftl[32][64];
  const int t = threadIdx.x;
  const int lane = t & 63;
  const int wave = t >> 6;
  const int np = blockIdx.x >> 7;
  const int ot = blockIdx.x & 127;
  const int o0 = ot * 64;
  const int hi = np >> 1;
  const int sb = (np & 1) * 64;

  #pragma unroll
  for (int q = 0; q < 8; ++q) {
    const int idx = q * 256 + t;
    ftl[idx >> 6][idx & 63] = ft[idx];
  }
  #pragma unroll
  for (int i = 0; i < 2; ++i) {
    const int r = (t >> 3) + 32 * i;
    const int g = t & 7;
    const unsigned* src = red32 + (size_t)(o0 + r) * 128 + sb + g * 8;
    const uint4 v0 = *(const uint4*)(src);
    const uint4 v1 = *(const uint4*)(src + 4);
    const unsigned w[8] = {v0.x, v0.y, v0.z, v0.w, v1.x, v1.y, v1.z, v1.w};
    float* dst = &rtile[r][g * 8];
    #pragma unroll
    for (int u = 0; u < 8; ++u)
      dst[u] = __uint_as_float(hi ? (w[u] & 0xffff0000u) : (w[u] << 16));
  }
  __syncthreads();

  const int n  = np * 2 + (wave & 1);
  const int kh = (wave >> 1) * 32;
  const int cb = (wave & 1) * 32;

  float rv[32];
  #pragma unroll
  for (int i = 0; i < 32; ++i) rv[i] = rtile[lane][cb + i];

  float acc[32];
  #pragma unroll
  for (int kk = 0; kk < 32; ++kk) acc[kk] = 0.f;
  #pragma unroll
  for (int i = 0; i < 32; ++i) {
    #pragma unroll
    for (int kk = 0; kk < 32; ++kk)
      acc[kk] += rv[i] * ftl[i][kh + kk];
  }

  float* op = out + (size_t)n * OUTC * OUTN + o0 + lane;
  const float* bp = bias + o0 + lane;
  #pragma unroll
  for (int kk = 0; kk < 32; ++kk) {
    const int k = kh + kk;
    op[(size_t)k * OUTN] = acc[kk] + bp[(size_t)k * OUTN];
  }
}

extern "C" void kernel_launch(void* const* d_in, const int* in_sizes, int n_in,
                              void* d_out, int out_size, void* d_ws, size_t ws_size,
                              hipStream_t stream) {
  const float* x    = (const float*)d_in[0];
  const float* nf   = (const float*)d_in[1];
  const float* ft   = (const float*)d_in[2];
  const float* bias = (const float*)d_in[3];
  const int*   A    = (const int*)d_in[4];
  float* out = (float*)d_out;

  unsigned* yTc   = (unsigned*)d_ws;                           // 8 x 3.2 MB = 25.6 MB
  unsigned* red32 = (unsigned*)((char*)d_ws + NPL * PLDW * 4); // 8192*128*4 = 4.2 MB

  const float* x_a = x; const float* nf_a = nf; const int* A_a = A;
  const float* ft_a = ft; const float* bias_a = bias;
  unsigned* yTc_a = yTc; unsigned* red_a = red32; float* out_a = out;
  void* args[8] = {(void*)&x_a, (void*)&nf_a, (void*)&A_a, (void*)&ft_a,
                   (void*)&bias_a, (void*)&yTc_a, (void*)&red_a, (void*)&out_a};
  hipError_t err = hipLaunchCooperativeKernel((void*)fused_kernel, dim3(2048), dim3(256),
                                              args, 0, stream);
  if (err != hipSuccess) {
    // fallback: proven 3-kernel path
    hipLaunchKernelGGL(prep_kernel,   dim3(((INN + JW - 1) / JW) * NPL), dim3(256), 0, stream, x, nf, yTc);
    hipLaunchKernelGGL(gather_kernel, dim3((OUTN / 32) * NPL),           dim3(256), 0, stream, yTc, A, red32);
    hipLaunchKernelGGL(out_kernel,    dim3(512),                         dim3(256), 0, stream, red32, ft, bias, out);
  }
}

// Round 18
// 52.945 us; speedup vs baseline: 9.5813x; 9.5813x over previous
//
#include <hip/hip_runtime.h>
#include <math.h>

#define NN   8
#define INCH 32
#define INN  50000
#define OUTC 64
#define OUTN 8192
#define DD   32
#define CC   256            // NN*INCH
#define NPL  8              // c-planes
#define PLDW ((size_t)INN * 16)   // dwords per plane: 50000 rows x 16 dwords(64B) = 3.2 MB
#define JW   16             // prep j-window; 50000 = 3125*16 exactly (no tail)

__device__ __forceinline__ unsigned f2bf_u(float f) {
  unsigned u = __float_as_uint(f);
  return (u + 0x7FFFu + ((u >> 16) & 1u)) >> 16;   // round-nearest-even
}

// dword convention: yTc plane p, row j, pos q (0..15) holds bf16 pair (c_lo, c_lo+128),
// c_lo = p*16 + q.

// Kernel 1: x*nf -> yTc. Occupancy-doubled prep: 17.4 KB LDS -> 8 blocks/CU = 32 waves/CU.
// Reads: per instr 16 rows x 64B; block covers 64 consecutive rows concurrently.
__global__ __launch_bounds__(256, 8) void prep_kernel(
    const float* __restrict__ x, const float* __restrict__ nf, unsigned* __restrict__ yTc) {
  __shared__ float tile[CC][17];   // 17408 B; stride 17 dwords -> <=2-way banks all phases
  const int t = threadIdx.x;
  const int j0 = blockIdx.x * JW;

  const int m  = t & 3;            // float4 within 16-j window
  const int r0 = t >> 2;           // 0..63

  {
    const float4 nv = *(const float4*)(nf + (size_t)(r0 & 31) * INN + j0 + 4 * m);  // invariant
    #pragma unroll
    for (int p = 0; p < 4; ++p) {
      const int c = (p << 6) + r0;
      const float4 xv = *(const float4*)(x + (size_t)c * INN + j0 + 4 * m);
      float4 pr;
      pr.x = xv.x * nv.x; pr.y = xv.y * nv.y; pr.z = xv.z * nv.z; pr.w = xv.w * nv.w;
      *(float4*)&tile[c][4 * m] = pr;   // bank (17c+4m+e)%32 -> <=2-way
    }
  }
  __syncthreads();

  // pack + store: 2048 dwords/block; per iter thread -> (plane pl, q, jl);
  // consecutive 16 threads cover one 64B yTc line; 4 lines per wave-instr.
  #pragma unroll
  for (int i = 0; i < 8; ++i) {
    const int dw = i * 256 + t;
    const int pl = dw >> 8;          // 0..7
    const int jl = (dw >> 4) & 15;
    const int q  = dw & 15;
    const int clo = pl * 16 + q;
    // LDS reads bank (16pl+17q+jl)%32 -> <=2-way
    const unsigned lo = f2bf_u(tile[clo][jl]);
    const unsigned hi = f2bf_u(tile[clo + 128][jl]);
    yTc[(size_t)pl * PLDW + (size_t)(j0 + jl) * 16 + q] = lo | (hi << 16);
  }
}

// Kernel 2 (R11, proven): c-sliced gather. 2048 blocks (plane=b%8, 32 o's), 8 blocks/CU.
__global__ __launch_bounds__(256, 8) void gather_kernel(
    const unsigned* __restrict__ yTc, const int* __restrict__ A, unsigned* __restrict__ red32) {
  __shared__ int Al[32 * 33];   // A[o0..o0+31][0..31], padded
  const int t = threadIdx.x;
  const int ck = blockIdx.x & 7;
  const int ob = blockIdx.x >> 3;   // 0..255
  const int o0 = ob * 32;

  #pragma unroll
  for (int k = 0; k < 4; ++k) {
    const int f = k * 256 + t;                      // 0..1023, coalesced
    Al[(f >> 5) * 33 + (f & 31)] = A[(size_t)o0 * DD + f];
  }
  __syncthreads();

  const unsigned* plane = yTc + (size_t)ck * PLDW;
  const int osub = t >> 3;          // 0..31
  const int cq   = (t >> 1) & 3;    // 0..3
  const int dh   = t & 1;           // 0..1

  float l0 = -INFINITY, l1 = -INFINITY, l2 = -INFINITY, l3 = -INFINITY;
  float h0 = -INFINITY, h1 = -INFINITY, h2 = -INFINITY, h3 = -INFINITY;

  #pragma unroll 8
  for (int k = 0; k < 16; ++k) {
    const int d = 2 * k + dh;
    const int idx = Al[osub * 33 + d];   // conflict-free broadcast
    const uint4 v = *(const uint4*)(plane + (size_t)idx * 16 + cq * 4);  // 16x64B segs/instr
    l0 = fmaxf(l0, __uint_as_float(v.x << 16));  h0 = fmaxf(h0, __uint_as_float(v.x & 0xffff0000u));
    l1 = fmaxf(l1, __uint_as_float(v.y << 16));  h1 = fmaxf(h1, __uint_as_float(v.y & 0xffff0000u));
    l2 = fmaxf(l2, __uint_as_float(v.z << 16));  h2 = fmaxf(h2, __uint_as_float(v.z & 0xffff0000u));
    l3 = fmaxf(l3, __uint_as_float(v.w << 16));  h3 = fmaxf(h3, __uint_as_float(v.w & 0xffff0000u));
  }
  // merge lane pairs (t, t^1)
  l0 = fmaxf(l0, __shfl_xor(l0, 1));  h0 = fmaxf(h0, __shfl_xor(h0, 1));
  l1 = fmaxf(l1, __shfl_xor(l1, 1));  h1 = fmaxf(h1, __shfl_xor(h1, 1));
  l2 = fmaxf(l2, __shfl_xor(l2, 1));  h2 = fmaxf(h2, __shfl_xor(h2, 1));
  l3 = fmaxf(l3, __shfl_xor(l3, 1));  h3 = fmaxf(h3, __shfl_xor(h3, 1));

  uint2 pk;
  if (dh == 0) {
    pk.x = (__float_as_uint(l0) >> 16) | (__float_as_uint(h0) & 0xffff0000u);
    pk.y = (__float_as_uint(l1) >> 16) | (__float_as_uint(h1) & 0xffff0000u);
  } else {
    pk.x = (__float_as_uint(l2) >> 16) | (__float_as_uint(h2) & 0xffff0000u);
    pk.y = (__float_as_uint(l3) >> 16) | (__float_as_uint(h3) & 0xffff0000u);
  }
  *(uint2*)(red32 + (size_t)(o0 + osub) * 128 + ck * 16 + cq * 4 + dh * 2) = pk;
}

// Kernel 3 (proven): out[n,k,o] = sum_i red[o][n*32+i]*ft[i][k] + bias[k][o]
__global__ __launch_bounds__(256) void out_kernel(
    const unsigned* __restrict__ red32, const float* __restrict__ ft,
    const float* __restrict__ bias, float* __restrict__ out) {
  __shared__ float rtile[64][65];   // pad 65 -> <=2-way
  __shared__ float ftl[32][64];
  const int t = threadIdx.x;
  const int lane = t & 63;
  const int wave = t >> 6;
  const int np = blockIdx.x >> 7;   // 0..3
  const int ot = blockIdx.x & 127;  // 0..127
  const int o0 = ot * 64;
  const int hi = np >> 1;
  const int sb = (np & 1) * 64;

  #pragma unroll
  for (int q = 0; q < 8; ++q) {
    const int idx = q * 256 + t;
    ftl[idx >> 6][idx & 63] = ft[idx];
  }
  #pragma unroll
  for (int i = 0; i < 2; ++i) {
    const int r = (t >> 3) + 32 * i;
    const int g = t & 7;
    const unsigned* src = red32 + (size_t)(o0 + r) * 128 + sb + g * 8;
    const uint4 v0 = *(const uint4*)(src);
    const uint4 v1 = *(const uint4*)(src + 4);
    const unsigned w[8] = {v0.x, v0.y, v0.z, v0.w, v1.x, v1.y, v1.z, v1.w};
    float* dst = &rtile[r][g * 8];
    #pragma unroll
    for (int u = 0; u < 8; ++u)
      dst[u] = __uint_as_float(hi ? (w[u] & 0xffff0000u) : (w[u] << 16));
  }
  __syncthreads();

  const int n  = np * 2 + (wave & 1);
  const int kh = (wave >> 1) * 32;
  const int cb = (wave & 1) * 32;

  float rv[32];
  #pragma unroll
  for (int i = 0; i < 32; ++i) rv[i] = rtile[lane][cb + i];   // 2-way

  float acc[32];
  #pragma unroll
  for (int kk = 0; kk < 32; ++kk) acc[kk] = 0.f;
  #pragma unroll
  for (int i = 0; i < 32; ++i) {
    #pragma unroll
    for (int kk = 0; kk < 32; ++kk)
      acc[kk] += rv[i] * ftl[i][kh + kk];   // uniform addr -> broadcast
  }

  float* op = out + (size_t)n * OUTC * OUTN + o0 + lane;
  const float* bp = bias + o0 + lane;
  #pragma unroll
  for (int kk = 0; kk < 32; ++kk) {
    const int k = kh + kk;
    op[(size_t)k * OUTN] = acc[kk] + bp[(size_t)k * OUTN];   // 256B-contiguous stores
  }
}

extern "C" void kernel_launch(void* const* d_in, const int* in_sizes, int n_in,
                              void* d_out, int out_size, void* d_ws, size_t ws_size,
                              hipStream_t stream) {
  const float* x    = (const float*)d_in[0];
  const float* nf   = (const float*)d_in[1];
  const float* ft   = (const float*)d_in[2];
  const float* bias = (const float*)d_in[3];
  const int*   A    = (const int*)d_in[4];
  float* out = (float*)d_out;

  unsigned* yTc   = (unsigned*)d_ws;                           // 8 x 3.2 MB = 25.6 MB
  unsigned* red32 = (unsigned*)((char*)d_ws + NPL * PLDW * 4); // 8192*128*4 = 4.2 MB

  hipLaunchKernelGGL(prep_kernel,   dim3(INN / JW),          dim3(256), 0, stream, x, nf, yTc);
  hipLaunchKernelGGL(gather_kernel, dim3((OUTN / 32) * NPL), dim3(256), 0, stream, yTc, A, red32);
  hipLaunchKernelGGL(out_kernel,    dim3(512),               dim3(256), 0, stream, red32, ft, bias, out);
}

// Round 19
// 46.267 us; speedup vs baseline: 10.9643x; 1.1443x over previous
//
#include <hip/hip_runtime.h>
#include <math.h>

#define NN   8
#define INCH 32
#define INN  50000
#define OUTC 64
#define OUTN 8192
#define DD   32
#define CC   256            // NN*INCH
#define NPL  8              // c-planes
#define PLDW ((size_t)INN * 16)   // dwords per plane: 50000 rows x 16 dwords(64B) = 3.2 MB

typedef unsigned short ushortT;

__device__ __forceinline__ unsigned f2bf_u(float f) {
  unsigned u = __float_as_uint(f);
  return (u + 0x7FFFu + ((u >> 16) & 1u)) >> 16;   // round-nearest-even
}

// dword convention: yTc plane p, row j, pos q (0..15) holds bf16 pair (c_lo, c_lo+128),
// c_lo = p*16 + q.

// Kernel 1 (best measured, R14): x*nf -> yTc. 64-col j-window, 16 lanes/row ->
// 4 rows x 256B contiguous per wave-instr, 16 independent passes (MLP).
__global__ __launch_bounds__(256) void prep_kernel(
    const float* __restrict__ x, const float* __restrict__ nf, unsigned* __restrict__ yTc) {
  __shared__ ushortT tile[CC][70];   // 35 KB; stride 70 ushorts (35 dwords, odd) -> <=2-way
  const int t = threadIdx.x;
  const int j0 = blockIdx.x * 64;
  const int jmax = min(64, INN - j0);   // 50000 = 781*64 + 16 -> last block 16
  const int m  = t & 15;    // float4-col within window
  const int r0 = t >> 4;    // 0..15
  const int lane = t & 63;
  const int wave = t >> 6;

  if (4 * m < jmax) {
    // nf row = c&31: p even -> r0, p odd -> r0+16 (two hoisted loads)
    const float4 nv0 = *(const float4*)(nf + (size_t)r0 * INN + j0 + 4 * m);
    const float4 nv1 = *(const float4*)(nf + (size_t)(r0 + 16) * INN + j0 + 4 * m);
    #pragma unroll 8
    for (int p = 0; p < 16; ++p) {
      const int c = (p << 4) + r0;
      const float4 xv = *(const float4*)(x + (size_t)c * INN + j0 + 4 * m);  // 256B/row seg
      const float4 nv = (p & 1) ? nv1 : nv0;
      // two 4B-aligned dword writes; banks (35c+2m+s)%32, rw-parity mixed -> <=2-way
      *(unsigned*)&tile[c][4 * m]     = f2bf_u(xv.x * nv.x) | (f2bf_u(xv.y * nv.y) << 16);
      *(unsigned*)&tile[c][4 * m + 2] = f2bf_u(xv.z * nv.z) | (f2bf_u(xv.w * nv.w) << 16);
    }
  }
  __syncthreads();

  // store (proven shape): per instr lane l -> clo=l+64e; 4 planes x 64B segments
  #pragma unroll
  for (int rr = 0; rr < 16; ++rr) {
    const int jl = wave * 16 + rr;
    if (jl < jmax) {
      #pragma unroll
      for (int e = 0; e < 2; ++e) {
        const int clo = lane + 64 * e;               // 0..127
        // ushort reads bank (3*clo + (jl>>1))%32 -> uniform 2-way (free)
        const unsigned lo = tile[clo][jl];
        const unsigned hi = tile[clo + 128][jl];
        yTc[(size_t)(clo >> 4) * PLDW + (size_t)(j0 + jl) * 16 + (clo & 15)] = lo | (hi << 16);
      }
    }
  }
}

// Kernel 2 (R11, proven): c-sliced gather. 2048 blocks (plane=b%8, 32 o's), 8 blocks/CU.
__global__ __launch_bounds__(256, 8) void gather_kernel(
    const unsigned* __restrict__ yTc, const int* __restrict__ A, unsigned* __restrict__ red32) {
  __shared__ int Al[32 * 33];   // A[o0..o0+31][0..31], padded
  const int t = threadIdx.x;
  const int ck = blockIdx.x & 7;
  const int ob = blockIdx.x >> 3;   // 0..255
  const int o0 = ob * 32;

  #pragma unroll
  for (int k = 0; k < 4; ++k) {
    const int f = k * 256 + t;                      // 0..1023, coalesced
    Al[(f >> 5) * 33 + (f & 31)] = A[(size_t)o0 * DD + f];
  }
  __syncthreads();

  const unsigned* plane = yTc + (size_t)ck * PLDW;
  const int osub = t >> 3;          // 0..31
  const int cq   = (t >> 1) & 3;    // 0..3
  const int dh   = t & 1;           // 0..1

  float l0 = -INFINITY, l1 = -INFINITY, l2 = -INFINITY, l3 = -INFINITY;
  float h0 = -INFINITY, h1 = -INFINITY, h2 = -INFINITY, h3 = -INFINITY;

  #pragma unroll 8
  for (int k = 0; k < 16; ++k) {
    const int d = 2 * k + dh;
    const int idx = Al[osub * 33 + d];   // conflict-free broadcast
    const uint4 v = *(const uint4*)(plane + (size_t)idx * 16 + cq * 4);  // 16x64B segs/instr
    l0 = fmaxf(l0, __uint_as_float(v.x << 16));  h0 = fmaxf(h0, __uint_as_float(v.x & 0xffff0000u));
    l1 = fmaxf(l1, __uint_as_float(v.y << 16));  h1 = fmaxf(h1, __uint_as_float(v.y & 0xffff0000u));
    l2 = fmaxf(l2, __uint_as_float(v.z << 16));  h2 = fmaxf(h2, __uint_as_float(v.z & 0xffff0000u));
    l3 = fmaxf(l3, __uint_as_float(v.w << 16));  h3 = fmaxf(h3, __uint_as_float(v.w & 0xffff0000u));
  }
  // merge lane pairs (t, t^1)
  l0 = fmaxf(l0, __shfl_xor(l0, 1));  h0 = fmaxf(h0, __shfl_xor(h0, 1));
  l1 = fmaxf(l1, __shfl_xor(l1, 1));  h1 = fmaxf(h1, __shfl_xor(h1, 1));
  l2 = fmaxf(l2, __shfl_xor(l2, 1));  h2 = fmaxf(h2, __shfl_xor(h2, 1));
  l3 = fmaxf(l3, __shfl_xor(l3, 1));  h3 = fmaxf(h3, __shfl_xor(h3, 1));

  uint2 pk;
  if (dh == 0) {
    pk.x = (__float_as_uint(l0) >> 16) | (__float_as_uint(h0) & 0xffff0000u);
    pk.y = (__float_as_uint(l1) >> 16) | (__float_as_uint(h1) & 0xffff0000u);
  } else {
    pk.x = (__float_as_uint(l2) >> 16) | (__float_as_uint(h2) & 0xffff0000u);
    pk.y = (__float_as_uint(l3) >> 16) | (__float_as_uint(h3) & 0xffff0000u);
  }
  *(uint2*)(red32 + (size_t)(o0 + osub) * 128 + ck * 16 + cq * 4 + dh * 2) = pk;
}

// Kernel 3 (proven): out[n,k,o] = sum_i red[o][n*32+i]*ft[i][k] + bias[k][o]
__global__ __launch_bounds__(256) void out_kernel(
    const unsigned* __restrict__ red32, const float* __restrict__ ft,
    const float* __restrict__ bias, float* __restrict__ out) {
  __shared__ float rtile[64][65];   // pad 65 -> <=2-way
  __shared__ float ftl[32][64];
  const int t = threadIdx.x;
  const int lane = t & 63;
  const int wave = t >> 6;
  const int np = blockIdx.x >> 7;   // 0..3
  const int ot = blockIdx.x & 127;  // 0..127
  const int o0 = ot * 64;
  const int hi = np >> 1;
  const int sb = (np & 1) * 64;

  #pragma unroll
  for (int q = 0; q < 8; ++q) {
    const int idx = q * 256 + t;
    ftl[idx >> 6][idx & 63] = ft[idx];
  }
  #pragma unroll
  for (int i = 0; i < 2; ++i) {
    const int r = (t >> 3) + 32 * i;
    const int g = t & 7;
    const unsigned* src = red32 + (size_t)(o0 + r) * 128 + sb + g * 8;
    const uint4 v0 = *(const uint4*)(src);
    const uint4 v1 = *(const uint4*)(src + 4);
    const unsigned w[8] = {v0.x, v0.y, v0.z, v0.w, v1.x, v1.y, v1.z, v1.w};
    float* dst = &rtile[r][g * 8];
    #pragma unroll
    for (int u = 0; u < 8; ++u)
      dst[u] = __uint_as_float(hi ? (w[u] & 0xffff0000u) : (w[u] << 16));
  }
  __syncthreads();

  const int n  = np * 2 + (wave & 1);
  const int kh = (wave >> 1) * 32;
  const int cb = (wave & 1) * 32;

  float rv[32];
  #pragma unroll
  for (int i = 0; i < 32; ++i) rv[i] = rtile[lane][cb + i];   // 2-way

  float acc[32];
  #pragma unroll
  for (int kk = 0; kk < 32; ++kk) acc[kk] = 0.f;
  #pragma unroll
  for (int i = 0; i < 32; ++i) {
    #pragma unroll
    for (int kk = 0; kk < 32; ++kk)
      acc[kk] += rv[i] * ftl[i][kh + kk];   // uniform addr -> broadcast
  }

  float* op = out + (size_t)n * OUTC * OUTN + o0 + lane;
  const float* bp = bias + o0 + lane;
  #pragma unroll
  for (int kk = 0; kk < 32; ++kk) {
    const int k = kh + kk;
    op[(size_t)k * OUTN] = acc[kk] + bp[(size_t)k * OUTN];   // 256B-contiguous stores
  }
}

extern "C" void kernel_launch(void* const* d_in, const int* in_sizes, int n_in,
                              void* d_out, int out_size, void* d_ws, size_t ws_size,
                              hipStream_t stream) {
  const float* x    = (const float*)d_in[0];
  const float* nf   = (const float*)d_in[1];
  const float* ft   = (const float*)d_in[2];
  const float* bias = (const float*)d_in[3];
  const int*   A    = (const int*)d_in[4];
  float* out = (float*)d_out;

  unsigned* yTc   = (unsigned*)d_ws;                           // 8 x 3.2 MB = 25.6 MB
  unsigned* red32 = (unsigned*)((char*)d_ws + NPL * PLDW * 4); // 8192*128*4 = 4.2 MB

  hipLaunchKernelGGL(prep_kernel,   dim3((INN + 63) / 64),   dim3(256), 0, stream, x, nf, yTc);
  hipLaunchKernelGGL(gather_kernel, dim3((OUTN / 32) * NPL), dim3(256), 0, stream, yTc, A, red32);
  hipLaunchKernelGGL(out_kernel,    dim3(512),               dim3(256), 0, stream, red32, ft, bias, out);
}